// Round 1
// baseline (253.639 us; speedup 1.0000x reference)
//
#include <hip/hip_runtime.h>
#include <hip/hip_bf16.h>

typedef __attribute__((ext_vector_type(8))) short short8;
typedef __attribute__((ext_vector_type(4))) float floatx4;

#define TOKENS 2048
#define IN_F   4096
#define OUT_F  4096
#define NITER  20

// round-to-nearest-even f32 -> bf16 bits
__device__ __forceinline__ unsigned short f2bf(float f) {
    unsigned int u = __builtin_bit_cast(unsigned int, f);
    u += 0x7fffu + ((u >> 16) & 1u);
    return (unsigned short)(u >> 16);
}

// Fused fractal-transcribe (ITERS=20) or plain cast (ITERS=0), f32 -> bf16, x4 vectorized.
template <int ITERS>
__global__ __launch_bounds__(256) void transcribe_kernel(
    const float4* __restrict__ in,
    const float* __restrict__ da, const float* __restrict__ db,
    ushort* __restrict__ out, int nvec)
{
    int i = blockIdx.x * 256 + threadIdx.x;
    if (i >= nvec) return;
    float4 w = in[i];
#pragma unroll
    for (int t = 0; t < ITERS; t++) {
        float a = da[t], b = db[t];   // uniform -> s_load
        w.x = a * w.x + b * __sinf(w.x);
        w.y = a * w.y + b * __sinf(w.y);
        w.z = a * w.z + b * __sinf(w.z);
        w.w = a * w.w + b * __sinf(w.w);
    }
    ushort4 o;
    o.x = f2bf(w.x); o.y = f2bf(w.y); o.z = f2bf(w.z); o.w = f2bf(w.w);
    *(ushort4*)(out + 4 * (size_t)i) = o;
}

// async 16B global -> LDS (wave-uniform base + lane*16 layout requirement honored by caller)
__device__ __forceinline__ void g2l16(const ushort* g, ushort* l) {
    __builtin_amdgcn_global_load_lds(
        (const __attribute__((address_space(1))) unsigned int*)g,
        (__attribute__((address_space(3))) unsigned int*)l, 16, 0, 0);
}

// C[M,N] = A[M,K] * B[N,K]^T + bias[N];  A,B bf16 (bits in ushort), C f32.
// 128x128 block tile, BK=32, 256 threads = 4 waves in 2x2, each wave 64x64 via
// 4x4 of v_mfma_f32_16x16x32_bf16. m97 ladder structure.
__global__ __launch_bounds__(256) void gemm_bt_kernel(
    const ushort* __restrict__ A,
    const ushort* __restrict__ B,
    const float* __restrict__ bias,
    float* __restrict__ C,
    int M, int N, int K)
{
    __shared__ ushort As[128 * 32];   // 8 KiB, row-major [row][k], 64 B/row, NO pad (global_load_lds)
    __shared__ ushort Bs[128 * 32];

    const int tid  = threadIdx.x;
    const int lane = tid & 63;
    const int wid  = tid >> 6;
    const int bn   = blockIdx.x;
    const int bm   = blockIdx.y;
    const int wm   = (wid >> 1) << 6;       // wave row offset in tile: 0/64
    const int wn   = (wid & 1) << 6;        // wave col offset: 0/64
    const int fm   = lane & 15;             // A/B operand: m (or n) = lane&15
    const int fk   = (lane >> 4) << 3;      // k = quad*8 + j

    // staging: thread t covers 16B chunk t of the 8 KiB tile -> lds byte off = tid*16
    const int row0 = tid >> 2;              // 0..63
    const int seg  = (tid & 3) << 3;        // element offset in row (8 bf16 = 16 B)

    const ushort* gA = A + (size_t)(bm * 128) * K;
    const ushort* gB = B + (size_t)(bn * 128) * K;

    floatx4 acc[4][4];
#pragma unroll
    for (int i = 0; i < 4; i++)
#pragma unroll
        for (int j = 0; j < 4; j++)
            acc[i][j] = (floatx4){0.f, 0.f, 0.f, 0.f};

    for (int k0 = 0; k0 < K; k0 += 32) {
        g2l16(gA + (size_t)row0 * K + k0 + seg,        As + row0 * 32 + seg);
        g2l16(gA + (size_t)(row0 + 64) * K + k0 + seg, As + (row0 + 64) * 32 + seg);
        g2l16(gB + (size_t)row0 * K + k0 + seg,        Bs + row0 * 32 + seg);
        g2l16(gB + (size_t)(row0 + 64) * K + k0 + seg, Bs + (row0 + 64) * 32 + seg);
        __syncthreads();   // compiler emits vmcnt(0) drain before barrier

        short8 af[4], bfr[4];
#pragma unroll
        for (int i = 0; i < 4; i++)
            af[i] = *(const short8*)(As + (wm + i * 16 + fm) * 32 + fk);
#pragma unroll
        for (int j = 0; j < 4; j++)
            bfr[j] = *(const short8*)(Bs + (wn + j * 16 + fm) * 32 + fk);
#pragma unroll
        for (int i = 0; i < 4; i++)
#pragma unroll
            for (int j = 0; j < 4; j++)
                acc[i][j] = __builtin_amdgcn_mfma_f32_16x16x32_bf16(
                    af[i], bfr[j], acc[i][j], 0, 0, 0);
        __syncthreads();
    }

    // epilogue: C/D layout col = lane&15, row = (lane>>4)*4 + reg  [m89-verified]
    const int cn = lane & 15;
    const int cm = (lane >> 4) << 2;
    float bv[4];
#pragma unroll
    for (int j = 0; j < 4; j++)
        bv[j] = bias[bn * 128 + wn + j * 16 + cn];
#pragma unroll
    for (int i = 0; i < 4; i++) {
#pragma unroll
        for (int r = 0; r < 4; r++) {
            int m = bm * 128 + wm + i * 16 + cm + r;
            float* crow = C + (size_t)m * N + bn * 128 + wn + cn;
#pragma unroll
            for (int j = 0; j < 4; j++)
                crow[j * 16] = acc[i][j][r] + bv[j];
        }
    }
}

extern "C" void kernel_launch(void* const* d_in, const int* in_sizes, int n_in,
                              void* d_out, int out_size, void* d_ws, size_t ws_size,
                              hipStream_t stream) {
    const float* x    = (const float*)d_in[0];   // [2048, 4096]
    const float* seed = (const float*)d_in[1];   // [4096, 4096]
    const float* da   = (const float*)d_in[2];   // [20]
    const float* db   = (const float*)d_in[3];   // [20]
    const float* bias = (const float*)d_in[4];   // [4096]
    float* out        = (float*)d_out;           // [2048, 4096]

    // workspace: weight bf16 (32 MiB) then x bf16 (16 MiB); both rewritten every call
    ushort* w_bf = (ushort*)d_ws;
    ushort* x_bf = w_bf + (size_t)OUT_F * IN_F;

    const int nvec_w = OUT_F * IN_F / 4;   // 4,194,304
    const int nvec_x = TOKENS * IN_F / 4;  // 2,097,152

    transcribe_kernel<NITER><<<nvec_w / 256, 256, 0, stream>>>(
        (const float4*)seed, da, db, w_bf, nvec_w);
    transcribe_kernel<0><<<nvec_x / 256, 256, 0, stream>>>(
        (const float4*)x, da, db, x_bf, nvec_x);

    dim3 grid(OUT_F / 128, TOKENS / 128);  // (32, 16) = 512 blocks
    gemm_bt_kernel<<<grid, 256, 0, stream>>>(x_bf, w_bf, bias, out,
                                             TOKENS, OUT_F, IN_F);
}

// Round 2
// 249.269 us; speedup vs baseline: 1.0175x; 1.0175x over previous
//
#include <hip/hip_runtime.h>
#include <hip/hip_bf16.h>

typedef __attribute__((ext_vector_type(8))) short short8;
typedef __attribute__((ext_vector_type(4))) float floatx4;

#define TOKENS 2048
#define IN_F   4096
#define OUT_F  4096
#define NITER  20

#define INV_2PI 0.15915494309189535f  // inline const 0.159154943 on gfx950

// round-to-nearest-even f32 -> bf16 bits
__device__ __forceinline__ unsigned short f2bf(float f) {
    unsigned int u = __builtin_bit_cast(unsigned int, f);
    u += 0x7fffu + ((u >> 16) & 1u);
    return (unsigned short)(u >> 16);
}

// hardware sin: v_sin_f32 takes revolutions; |w| stays O(5) so no range reduction needed
__device__ __forceinline__ float hw_sin(float x) {
    return __builtin_amdgcn_sinf(x * INV_2PI);
}

// Fused fractal-transcribe (ITERS=20) or plain cast (ITERS=0), f32 -> bf16, x4 vectorized.
template <int ITERS>
__global__ __launch_bounds__(256) void transcribe_kernel(
    const float4* __restrict__ in,
    const float* __restrict__ da, const float* __restrict__ db,
    ushort* __restrict__ out, int nvec)
{
    int i = blockIdx.x * 256 + threadIdx.x;
    if (i >= nvec) return;
    float4 w = in[i];
#pragma unroll
    for (int t = 0; t < ITERS; t++) {
        float a = da[t], b = db[t];   // uniform -> s_load
        w.x = a * w.x + b * hw_sin(w.x);
        w.y = a * w.y + b * hw_sin(w.y);
        w.z = a * w.z + b * hw_sin(w.z);
        w.w = a * w.w + b * hw_sin(w.w);
    }
    ushort4 o;
    o.x = f2bf(w.x); o.y = f2bf(w.y); o.z = f2bf(w.z); o.w = f2bf(w.w);
    *(ushort4*)(out + 4 * (size_t)i) = o;
}

// async 16B global -> LDS (LDS dest must be linear: wave-uniform base + lane*16)
__device__ __forceinline__ void g2l16(const ushort* g, ushort* l) {
    __builtin_amdgcn_global_load_lds(
        (const __attribute__((address_space(1))) unsigned int*)g,
        (__attribute__((address_space(3))) unsigned int*)l, 16, 0, 0);
}

// C[M,N] = A[M,K] * B[N,K]^T + bias[N];  A,B bf16 (bits in ushort), C f32.
// 128x128 block tile, BK=32, 256 threads = 4 waves in 2x2, each wave 64x64 via
// 4x4 of v_mfma_f32_16x16x32_bf16.
// LDS bank-conflict fix: physical 16B segment p of row r holds LOGICAL segment
// p ^ ((r>>1)&3) (swizzle applied on the global-source side of global_load_lds,
// and on the ds_read address side; LDS dest stays linear as required).
__global__ __launch_bounds__(256) void gemm_bt_kernel(
    const ushort* __restrict__ A,
    const ushort* __restrict__ B,
    const float* __restrict__ bias,
    float* __restrict__ C,
    int M, int N, int K)
{
    __shared__ ushort As[128 * 32];   // 8 KiB, row-major [row][k-seg swizzled]
    __shared__ ushort Bs[128 * 32];

    const int tid  = threadIdx.x;
    const int lane = tid & 63;
    const int wid  = tid >> 6;
    const int bn   = blockIdx.x;
    const int bm   = blockIdx.y;
    const int wm   = (wid >> 1) << 6;       // wave row offset in tile: 0/64
    const int wn   = (wid & 1) << 6;        // wave col offset: 0/64
    const int fm   = lane & 15;             // A/B operand: m (or n) = lane&15
    // logical k-segment = quad (lane>>4); physical = quad ^ ((row>>1)&3).
    // row = (mult of 16) + fm  ->  (row>>1)&3 == (fm>>1)&3
    const int fkd  = (((lane >> 4) ^ ((fm >> 1) & 3)) << 3); // swizzled k elem offset

    // staging: thread t covers physical 16B segment (t&3) of row (t>>2);
    // its global source is the swizzled logical segment.
    const int row0 = tid >> 2;              // 0..63
    const int psg  = tid & 3;               // physical segment
    const int gsg  = (psg ^ ((row0 >> 1) & 3)) << 3;  // global elem offset in row
    const int lsg  = psg << 3;              // lds elem offset in row (linear!)

    const ushort* gA = A + (size_t)(bm * 128) * K;
    const ushort* gB = B + (size_t)(bn * 128) * K;

    floatx4 acc[4][4];
#pragma unroll
    for (int i = 0; i < 4; i++)
#pragma unroll
        for (int j = 0; j < 4; j++)
            acc[i][j] = (floatx4){0.f, 0.f, 0.f, 0.f};

    for (int k0 = 0; k0 < K; k0 += 32) {
        // note: (row0+64)>>1 & 3 == (row0>>1)&3 since 32 % 4 == 0 -> same gsg
        g2l16(gA + (size_t)row0 * K + k0 + gsg,        As + row0 * 32 + lsg);
        g2l16(gA + (size_t)(row0 + 64) * K + k0 + gsg, As + (row0 + 64) * 32 + lsg);
        g2l16(gB + (size_t)row0 * K + k0 + gsg,        Bs + row0 * 32 + lsg);
        g2l16(gB + (size_t)(row0 + 64) * K + k0 + gsg, Bs + (row0 + 64) * 32 + lsg);
        __syncthreads();

        short8 af[4], bfr[4];
#pragma unroll
        for (int i = 0; i < 4; i++)
            af[i] = *(const short8*)(As + (wm + i * 16 + fm) * 32 + fkd);
#pragma unroll
        for (int j = 0; j < 4; j++)
            bfr[j] = *(const short8*)(Bs + (wn + j * 16 + fm) * 32 + fkd);
#pragma unroll
        for (int i = 0; i < 4; i++)
#pragma unroll
            for (int j = 0; j < 4; j++)
                acc[i][j] = __builtin_amdgcn_mfma_f32_16x16x32_bf16(
                    af[i], bfr[j], acc[i][j], 0, 0, 0);
        __syncthreads();
    }

    // epilogue: C/D layout col = lane&15, row = (lane>>4)*4 + reg  [m89-verified]
    const int cn = lane & 15;
    const int cm = (lane >> 4) << 2;
    float bv[4];
#pragma unroll
    for (int j = 0; j < 4; j++)
        bv[j] = bias[bn * 128 + wn + j * 16 + cn];
#pragma unroll
    for (int i = 0; i < 4; i++) {
#pragma unroll
        for (int r = 0; r < 4; r++) {
            int m = bm * 128 + wm + i * 16 + cm + r;
            float* crow = C + (size_t)m * N + bn * 128 + wn + cn;
#pragma unroll
            for (int j = 0; j < 4; j++)
                crow[j * 16] = acc[i][j][r] + bv[j];
        }
    }
}

extern "C" void kernel_launch(void* const* d_in, const int* in_sizes, int n_in,
                              void* d_out, int out_size, void* d_ws, size_t ws_size,
                              hipStream_t stream) {
    const float* x    = (const float*)d_in[0];   // [2048, 4096]
    const float* seed = (const float*)d_in[1];   // [4096, 4096]
    const float* da   = (const float*)d_in[2];   // [20]
    const float* db   = (const float*)d_in[3];   // [20]
    const float* bias = (const float*)d_in[4];   // [4096]
    float* out        = (float*)d_out;           // [2048, 4096]

    // workspace: weight bf16 (32 MiB) then x bf16 (16 MiB); both rewritten every call
    ushort* w_bf = (ushort*)d_ws;
    ushort* x_bf = w_bf + (size_t)OUT_F * IN_F;

    const int nvec_w = OUT_F * IN_F / 4;   // 4,194,304
    const int nvec_x = TOKENS * IN_F / 4;  // 2,097,152

    transcribe_kernel<NITER><<<nvec_w / 256, 256, 0, stream>>>(
        (const float4*)seed, da, db, w_bf, nvec_w);
    transcribe_kernel<0><<<nvec_x / 256, 256, 0, stream>>>(
        (const float4*)x, da, db, x_bf, nvec_x);

    dim3 grid(OUT_F / 128, TOKENS / 128);  // (32, 16) = 512 blocks
    gemm_bt_kernel<<<grid, 256, 0, stream>>>(x_bf, w_bf, bias, out,
                                             TOKENS, OUT_F, IN_F);
}

// Round 3
// 242.336 us; speedup vs baseline: 1.0466x; 1.0286x over previous
//
#include <hip/hip_runtime.h>
#include <hip/hip_bf16.h>

typedef __attribute__((ext_vector_type(8))) short short8;
typedef __attribute__((ext_vector_type(4))) float floatx4;

#define TOKENS 2048
#define IN_F   4096
#define OUT_F  4096
#define NITER  20

#define INV_2PI 0.15915494309189535f
#define TWO_PI  6.283185307179586f

// round-to-nearest-even f32 -> bf16 bits
__device__ __forceinline__ unsigned short f2bf(float f) {
    unsigned int u = __builtin_bit_cast(unsigned int, f);
    u += 0x7fffu + ((u >> 16) & 1u);
    return (unsigned short)(u >> 16);
}

// one fractal step in REVOLUTION units: v' = a*v + (b/2pi)*sin(2pi*v)
__device__ __forceinline__ void step4(float4& v, float a, float bc) {
    v.x = __builtin_fmaf(bc, __builtin_amdgcn_sinf(v.x), a * v.x);
    v.y = __builtin_fmaf(bc, __builtin_amdgcn_sinf(v.y), a * v.y);
    v.z = __builtin_fmaf(bc, __builtin_amdgcn_sinf(v.z), a * v.z);
    v.w = __builtin_fmaf(bc, __builtin_amdgcn_sinf(v.w), a * v.w);
}

// Fractal transcribe (ITERS=20) or plain cast (ITERS=0): f32 -> bf16,
// 8 elems/thread = two independent float4 chains, one 16B store.
template <int ITERS>
__global__ __launch_bounds__(256) void transcribe_kernel(
    const float4* __restrict__ in,
    const float* __restrict__ da, const float* __restrict__ db,
    short8* __restrict__ out, int n8)
{
    int i = blockIdx.x * 256 + threadIdx.x;
    if (i >= n8) return;
    float4 u = in[2 * i];
    float4 v = in[2 * i + 1];
    float fin = 1.0f;
    if (ITERS > 0) {
        u.x *= INV_2PI; u.y *= INV_2PI; u.z *= INV_2PI; u.w *= INV_2PI;
        v.x *= INV_2PI; v.y *= INV_2PI; v.z *= INV_2PI; v.w *= INV_2PI;
#pragma unroll
        for (int t = 0; t < ITERS; t++) {
            float a = da[t], bc = db[t] * INV_2PI;  // uniform scalar math
            step4(u, a, bc);
            step4(v, a, bc);
        }
        fin = TWO_PI;
    }
    short8 o;
    o[0] = (short)f2bf(u.x * fin); o[1] = (short)f2bf(u.y * fin);
    o[2] = (short)f2bf(u.z * fin); o[3] = (short)f2bf(u.w * fin);
    o[4] = (short)f2bf(v.x * fin); o[5] = (short)f2bf(v.y * fin);
    o[6] = (short)f2bf(v.z * fin); o[7] = (short)f2bf(v.w * fin);
    out[i] = o;
}

// async 16B global -> LDS (LDS dest must be linear: wave-uniform base + lane*16)
__device__ __forceinline__ void g2l16(const ushort* g, ushort* l) {
    __builtin_amdgcn_global_load_lds(
        (const __attribute__((address_space(1))) unsigned int*)g,
        (__attribute__((address_space(3))) unsigned int*)l, 16, 0, 0);
}

// C[M,N] = A[M,K] * B[N,K]^T + bias[N];  A,B bf16 (bits in ushort), C f32.
// 64x128 block tile (TMxTN), BK=32, 256 threads = 4 waves in 2x2; each wave
// 32x64 via 2x4 of v_mfma_f32_16x16x32_bf16. Grid = 32x32 = 1024 blocks
// -> 4 blocks/CU (vs 2 with 128x128): occupancy was the R2 gate.
// LDS swizzle: physical 16B segment p of row r holds LOGICAL segment
// p ^ ((r>>1)&3); applied on the global-source side and the ds_read side.
__global__ __launch_bounds__(256) void gemm_bt_kernel(
    const ushort* __restrict__ A,
    const ushort* __restrict__ B,
    const float* __restrict__ bias,
    float* __restrict__ C,
    int M, int N, int K)
{
    __shared__ ushort As[64 * 32];    // 4 KiB
    __shared__ ushort Bs[128 * 32];   // 8 KiB

    const int tid  = threadIdx.x;
    const int lane = tid & 63;
    const int wid  = tid >> 6;
    const int bn   = blockIdx.x;
    const int bm   = blockIdx.y;
    const int wm   = (wid >> 1) << 5;       // wave row offset: 0/32
    const int wn   = (wid & 1) << 6;        // wave col offset: 0/64
    const int fm   = lane & 15;
    // swizzled k elem offset: logical seg = quad, physical = quad ^ ((row>>1)&3),
    // and (row>>1)&3 == (fm>>1)&3 for every row we read (offsets are mult of 16/32/64)
    const int fkd  = (((lane >> 4) ^ ((fm >> 1) & 3)) << 3);

    // staging: thread t covers physical 16B segment (t&3) of row (t>>2)
    const int row0 = tid >> 2;              // 0..63
    const int psg  = tid & 3;
    const int gsg  = (psg ^ ((row0 >> 1) & 3)) << 3;  // global elem offset
    const int lsg  = psg << 3;                        // LDS elem offset (linear)

    const ushort* gA = A + (size_t)(bm * 64) * K;
    const ushort* gB = B + (size_t)(bn * 128) * K;

    floatx4 acc[2][4];
#pragma unroll
    for (int i = 0; i < 2; i++)
#pragma unroll
        for (int j = 0; j < 4; j++)
            acc[i][j] = (floatx4){0.f, 0.f, 0.f, 0.f};

    for (int k0 = 0; k0 < K; k0 += 32) {
        g2l16(gA + (size_t)row0 * K + k0 + gsg,        As + row0 * 32 + lsg);
        g2l16(gB + (size_t)row0 * K + k0 + gsg,        Bs + row0 * 32 + lsg);
        g2l16(gB + (size_t)(row0 + 64) * K + k0 + gsg, Bs + (row0 + 64) * 32 + lsg);
        __syncthreads();

        short8 af[2], bfr[4];
#pragma unroll
        for (int i = 0; i < 2; i++)
            af[i] = *(const short8*)(As + (wm + i * 16 + fm) * 32 + fkd);
#pragma unroll
        for (int j = 0; j < 4; j++)
            bfr[j] = *(const short8*)(Bs + (wn + j * 16 + fm) * 32 + fkd);
#pragma unroll
        for (int i = 0; i < 2; i++)
#pragma unroll
            for (int j = 0; j < 4; j++)
                acc[i][j] = __builtin_amdgcn_mfma_f32_16x16x32_bf16(
                    af[i], bfr[j], acc[i][j], 0, 0, 0);
        __syncthreads();
    }

    // epilogue: C/D layout col = lane&15, row = (lane>>4)*4 + reg  [m89-verified]
    const int cn = lane & 15;
    const int cm = (lane >> 4) << 2;
    float bv[4];
#pragma unroll
    for (int j = 0; j < 4; j++)
        bv[j] = bias[bn * 128 + wn + j * 16 + cn];
#pragma unroll
    for (int i = 0; i < 2; i++) {
#pragma unroll
        for (int r = 0; r < 4; r++) {
            int m = bm * 64 + wm + i * 16 + cm + r;
            float* crow = C + (size_t)m * N + bn * 128 + wn + cn;
#pragma unroll
            for (int j = 0; j < 4; j++)
                crow[j * 16] = acc[i][j][r] + bv[j];
        }
    }
}

extern "C" void kernel_launch(void* const* d_in, const int* in_sizes, int n_in,
                              void* d_out, int out_size, void* d_ws, size_t ws_size,
                              hipStream_t stream) {
    const float* x    = (const float*)d_in[0];   // [2048, 4096]
    const float* seed = (const float*)d_in[1];   // [4096, 4096]
    const float* da   = (const float*)d_in[2];   // [20]
    const float* db   = (const float*)d_in[3];   // [20]
    const float* bias = (const float*)d_in[4];   // [4096]
    float* out        = (float*)d_out;           // [2048, 4096]

    ushort* w_bf = (ushort*)d_ws;
    ushort* x_bf = w_bf + (size_t)OUT_F * IN_F;

    const int n8_w = OUT_F * IN_F / 8;   // 2,097,152
    const int n8_x = TOKENS * IN_F / 8;  // 1,048,576

    transcribe_kernel<NITER><<<n8_w / 256, 256, 0, stream>>>(
        (const float4*)seed, da, db, (short8*)w_bf, n8_w);
    transcribe_kernel<0><<<n8_x / 256, 256, 0, stream>>>(
        (const float4*)x, da, db, (short8*)x_bf, n8_x);

    dim3 grid(OUT_F / 128, TOKENS / 64);  // (32, 32) = 1024 blocks
    gemm_bt_kernel<<<grid, 256, 0, stream>>>(x_bf, w_bf, bias, out,
                                             TOKENS, OUT_F, IN_F);
}

// Round 5
// 215.700 us; speedup vs baseline: 1.1759x; 1.1235x over previous
//
#include <hip/hip_runtime.h>

typedef __attribute__((ext_vector_type(8))) short short8;
typedef __attribute__((ext_vector_type(4))) float floatx4;

#define TOKENS 2048
#define IN_F   4096
#define OUT_F  4096
#define NITER  20
#define BK     64

#define INV_2PI 0.15915494309189535f
#define TWO_PI  6.283185307179586f

// round-to-nearest-even f32 -> bf16 bits
__device__ __forceinline__ unsigned short f2bf(float f) {
    unsigned int u = __builtin_bit_cast(unsigned int, f);
    u += 0x7fffu + ((u >> 16) & 1u);
    return (unsigned short)(u >> 16);
}

// one fractal step in REVOLUTION units: v' = a*v + (b/2pi)*sin(2pi*v)
__device__ __forceinline__ void step4(float4& v, float a, float bc) {
    v.x = __builtin_fmaf(bc, __builtin_amdgcn_sinf(v.x), a * v.x);
    v.y = __builtin_fmaf(bc, __builtin_amdgcn_sinf(v.y), a * v.y);
    v.z = __builtin_fmaf(bc, __builtin_amdgcn_sinf(v.z), a * v.z);
    v.w = __builtin_fmaf(bc, __builtin_amdgcn_sinf(v.w), a * v.w);
}

#define WBLOCKS (OUT_F * IN_F / 8 / 256)   // 8192
#define XBLOCKS (TOKENS * IN_F / 8 / 256)  // 4096

// Fused: blocks [0,8192) transcribe seed->w_bf (20 iters); [8192,12288) cast x->x_bf.
__global__ __launch_bounds__(256) void transcribe_fused_kernel(
    const float4* __restrict__ seed, const float4* __restrict__ xin,
    const float* __restrict__ da, const float* __restrict__ db,
    short8* __restrict__ w_out, short8* __restrict__ x_out)
{
    const int b = blockIdx.x;
    short8 o;
    if (b < WBLOCKS) {
        int i = b * 256 + threadIdx.x;
        float4 u = seed[2 * i];
        float4 v = seed[2 * i + 1];
        u.x *= INV_2PI; u.y *= INV_2PI; u.z *= INV_2PI; u.w *= INV_2PI;
        v.x *= INV_2PI; v.y *= INV_2PI; v.z *= INV_2PI; v.w *= INV_2PI;
#pragma unroll
        for (int t = 0; t < NITER; t++) {
            float a = da[t], bc = db[t] * INV_2PI;
            step4(u, a, bc);
            step4(v, a, bc);
        }
        o[0] = (short)f2bf(u.x * TWO_PI); o[1] = (short)f2bf(u.y * TWO_PI);
        o[2] = (short)f2bf(u.z * TWO_PI); o[3] = (short)f2bf(u.w * TWO_PI);
        o[4] = (short)f2bf(v.x * TWO_PI); o[5] = (short)f2bf(v.y * TWO_PI);
        o[6] = (short)f2bf(v.z * TWO_PI); o[7] = (short)f2bf(v.w * TWO_PI);
        w_out[i] = o;
    } else {
        int i = (b - WBLOCKS) * 256 + threadIdx.x;
        float4 u = xin[2 * i];
        float4 v = xin[2 * i + 1];
        o[0] = (short)f2bf(u.x); o[1] = (short)f2bf(u.y);
        o[2] = (short)f2bf(u.z); o[3] = (short)f2bf(u.w);
        o[4] = (short)f2bf(v.x); o[5] = (short)f2bf(v.y);
        o[6] = (short)f2bf(v.z); o[7] = (short)f2bf(v.w);
        x_out[i] = o;
    }
}

// async 16B global -> LDS (LDS dest = wave-uniform base + lane*16, enforced below)
__device__ __forceinline__ void g2l16(const ushort* g, ushort* l) {
    __builtin_amdgcn_global_load_lds(
        (const __attribute__((address_space(1))) unsigned int*)g,
        (__attribute__((address_space(3))) unsigned int*)l, 16, 0, 0);
}

// C[M,N] = A[M,K] * B[N,K]^T + bias[N];  A,B bf16 (bits), C f32.
// 128x128 block tile, BK=64, DOUBLE-BUFFERED LDS (2 x (16+16) KB = 64 KB):
// slab k+1 is issued via global_load_lds a full compute window (~32 MFMAs/wave)
// before the barrier that drains it -> the vmcnt(0) exposure that gated R2/R3
// (measured ~1100 cyc/window at 2 blocks/CU) is overlapped; window count halves.
// Swizzle for 128B rows: physical 16B segment p of row r holds logical segment
// p ^ (r&7) (global-source side + ds_read side; LDS dest stays linear).
// Read pattern is bank-equivalent to a linear b128 sweep -> conflict-free.
__global__ __launch_bounds__(256, 2) void gemm_bt_kernel(
    const ushort* __restrict__ A,
    const ushort* __restrict__ B,
    const float* __restrict__ bias,
    float* __restrict__ C)
{
    __shared__ ushort As[2][128 * BK];   // 2 x 16 KiB
    __shared__ ushort Bs[2][128 * BK];   // 2 x 16 KiB

    const int tid  = threadIdx.x;
    const int lane = tid & 63;
    const int wid  = tid >> 6;
    const int bn   = blockIdx.x;
    const int bm   = blockIdx.y;
    const int wm   = (wid >> 1) << 6;    // 0/64
    const int wn   = (wid & 1) << 6;     // 0/64
    const int fm   = lane & 15;
    const int q    = lane >> 4;          // 0..3

    // staging: wave-instr u covers 64 consecutive 16B chunks; chunk c = row*8+pseg,
    // lane = (row&7)*8 + pseg. Global source segment = pseg ^ (row&7).
    const int gcol = (((lane & 7) ^ (lane >> 3)) << 3);  // swizzled elem offset in row

    const ushort* gA = A + (size_t)(bm * 128) * IN_F;
    const ushort* gB = B + (size_t)(bn * 128) * IN_F;

    floatx4 acc[4][4];
#pragma unroll
    for (int i = 0; i < 4; i++)
#pragma unroll
        for (int j = 0; j < 4; j++)
            acc[i][j] = (floatx4){0.f, 0.f, 0.f, 0.f};

#define STAGE(k0v, bufi)                                                      \
    {                                                                         \
        _Pragma("unroll")                                                     \
        for (int u = 0; u < 4; u++) {                                         \
            const int cb = ((u << 2) | wid) << 6;   /* chunk base */          \
            const int r  = (cb >> 3) + (lane >> 3); /* row 0..127 */          \
            g2l16(gA + (size_t)r * IN_F + (k0v) + gcol,                       \
                  &As[bufi][cb * 8 + lane * 8]);                              \
            g2l16(gB + (size_t)r * IN_F + (k0v) + gcol,                       \
                  &Bs[bufi][cb * 8 + lane * 8]);                              \
        }                                                                     \
    }

#define COMPUTE(bufi)                                                         \
    {                                                                         \
        _Pragma("unroll")                                                     \
        for (int s = 0; s < 2; s++) {                                         \
            short8 af[4], bf[4];                                              \
            const int sa = (((q + 4 * s) & 7) ^ (fm & 7)) << 3;               \
            _Pragma("unroll")                                                 \
            for (int i = 0; i < 4; i++) {                                     \
                af[i] = *(const short8*)&As[bufi][(wm + i * 16 + fm) * BK + sa]; \
                bf[i] = *(const short8*)&Bs[bufi][(wn + i * 16 + fm) * BK + sa]; \
            }                                                                 \
            _Pragma("unroll")                                                 \
            for (int i = 0; i < 4; i++)                                       \
                _Pragma("unroll")                                             \
                for (int j = 0; j < 4; j++)                                   \
                    acc[i][j] = __builtin_amdgcn_mfma_f32_16x16x32_bf16(      \
                        af[i], bf[j], acc[i][j], 0, 0, 0);                    \
        }                                                                     \
    }

    STAGE(0, 0);
    __syncthreads();
    STAGE(BK, 1);
    COMPUTE(0);
    __syncthreads();
    // 31 pairs: slabs 128..4032
    for (int k0 = 2 * BK; k0 < IN_F; k0 += 2 * BK) {
        STAGE(k0, 0);
        COMPUTE(1);
        __syncthreads();
        STAGE(k0 + BK, 1);
        COMPUTE(0);
        __syncthreads();
    }
    COMPUTE(1);

#undef STAGE
#undef COMPUTE

    // epilogue: C/D layout col = lane&15, row = (lane>>4)*4 + reg  [m89-verified]
    const int cn = lane & 15;
    const int cm = (lane >> 4) << 2;
    float bv[4];
#pragma unroll
    for (int j = 0; j < 4; j++)
        bv[j] = bias[bn * 128 + wn + j * 16 + cn];
#pragma unroll
    for (int i = 0; i < 4; i++) {
#pragma unroll
        for (int r = 0; r < 4; r++) {
            int m = bm * 128 + wm + i * 16 + cm + r;
            float* crow = C + (size_t)m * OUT_F + bn * 128 + wn + cn;
#pragma unroll
            for (int j = 0; j < 4; j++)
                crow[j * 16] = acc[i][j][r] + bv[j];
        }
    }
}

extern "C" void kernel_launch(void* const* d_in, const int* in_sizes, int n_in,
                              void* d_out, int out_size, void* d_ws, size_t ws_size,
                              hipStream_t stream) {
    const float* x    = (const float*)d_in[0];   // [2048, 4096]
    const float* seed = (const float*)d_in[1];   // [4096, 4096]
    const float* da   = (const float*)d_in[2];   // [20]
    const float* db   = (const float*)d_in[3];   // [20]
    const float* bias = (const float*)d_in[4];   // [4096]
    float* out        = (float*)d_out;           // [2048, 4096]

    ushort* w_bf = (ushort*)d_ws;                      // 32 MiB
    ushort* x_bf = w_bf + (size_t)OUT_F * IN_F;        // 16 MiB

    transcribe_fused_kernel<<<WBLOCKS + XBLOCKS, 256, 0, stream>>>(
        (const float4*)seed, (const float4*)x, da, db,
        (short8*)w_bf, (short8*)x_bf);

    dim3 grid(OUT_F / 128, TOKENS / 128);  // (32, 16) = 512 blocks
    gemm_bt_kernel<<<grid, 256, 0, stream>>>(x_bf, w_bf, bias, out);
}